// Round 2
// baseline (333.401 us; speedup 1.0000x reference)
//
#include <hip/hip_runtime.h>
#include <cstdint>

// Problem constants (x: [64, 768, 28, 28] fp32)
#define B_   64
#define C_   768
#define HID_ 192
#define HW_  784                 // 28*28
#define NCHAN (B_ * C_)          // 49152
#define VEC4_PER_CHAN (HW_ / 4)  // 196 float4 per channel
#define NVEC4 (NCHAN * VEC4_PER_CHAN)  // 9,633,792

// ---------- Kernel 1: global average pool. One wave (64 lanes) per (b,c). ----------
__global__ __launch_bounds__(256) void pool_kernel(const float* __restrict__ x,
                                                   float* __restrict__ pooled) {
    int wave = (blockIdx.x * blockDim.x + threadIdx.x) >> 6;   // channel index b*C+c
    int lane = threadIdx.x & 63;
    const float4* p = (const float4*)(x + (size_t)wave * HW_); // 196 x 16B, 16B-aligned
    float sum = 0.f;
    for (int f = lane; f < VEC4_PER_CHAN; f += 64) {
        float4 v = p[f];
        sum += v.x + v.y + v.z + v.w;
    }
    #pragma unroll
    for (int off = 32; off > 0; off >>= 1) sum += __shfl_down(sum, off, 64);
    if (lane == 0) pooled[wave] = sum * (1.0f / (float)HW_);
}

// ---------- Kernel 2: FC1+ReLU -> FC2+hardsigmoid. One block per batch. ----------
__global__ __launch_bounds__(256) void fc_kernel(const float* __restrict__ pooled,
                                                 const float* __restrict__ w1,
                                                 const float* __restrict__ b1,
                                                 const float* __restrict__ w2,
                                                 const float* __restrict__ b2,
                                                 float* __restrict__ s_out) {
    __shared__ float sp[C_];
    __shared__ float sh[HID_];
    int b = blockIdx.x;
    int t = threadIdx.x;
    for (int i = t; i < C_; i += 256) sp[i] = pooled[b * C_ + i];
    __syncthreads();

    if (t < HID_) {
        const float4* row = (const float4*)(w1 + (size_t)t * C_);  // 192 x 16B
        float acc = 0.f;
        #pragma unroll 4
        for (int f = 0; f < C_ / 4; ++f) {
            float4 v = row[f];
            const float* pp = &sp[f * 4];
            acc += v.x * pp[0] + v.y * pp[1] + v.z * pp[2] + v.w * pp[3];
        }
        float h = acc + b1[t];
        sh[t] = h > 0.f ? h : 0.f;
    }
    __syncthreads();

    for (int j = t; j < C_; j += 256) {
        const float4* row = (const float4*)(w2 + (size_t)j * HID_);  // 48 x 16B
        float acc = 0.f;
        #pragma unroll 4
        for (int f = 0; f < HID_ / 4; ++f) {
            float4 v = row[f];
            const float* pp = &sh[f * 4];
            acc += v.x * pp[0] + v.y * pp[1] + v.z * pp[2] + v.w * pp[3];
        }
        float z = acc + b2[j];
        float sg = z * (1.0f / 6.0f) + 0.5f;
        sg = sg < 0.f ? 0.f : (sg > 1.f ? 1.f : sg);
        s_out[b * C_ + j] = sg;
    }
}

// ---------- Kernel 3: out = x * s[b,c], one float4 per thread ----------
__global__ __launch_bounds__(256) void scale_kernel(const float* __restrict__ x,
                                                    const float* __restrict__ s,
                                                    float* __restrict__ out) {
    int f = blockIdx.x * 256 + threadIdx.x;
    if (f >= NVEC4) return;
    float sc = s[f / VEC4_PER_CHAN];   // constant divide -> magic mul
    float4 v = ((const float4*)x)[f];
    v.x *= sc; v.y *= sc; v.z *= sc; v.w *= sc;
    ((float4*)out)[f] = v;
}

extern "C" void kernel_launch(void* const* d_in, const int* in_sizes, int n_in,
                              void* d_out, int out_size, void* d_ws, size_t ws_size,
                              hipStream_t stream) {
    const float* x  = (const float*)d_in[0];
    const float* w1 = (const float*)d_in[1];
    const float* b1 = (const float*)d_in[2];
    const float* w2 = (const float*)d_in[3];
    const float* b2 = (const float*)d_in[4];
    float* out = (float*)d_out;

    float* pooled = (float*)d_ws;             // 49152 fp32 = 192 KiB
    float* s      = (float*)d_ws + NCHAN;     // 49152 fp32 = 192 KiB

    // 1) pool: one wave per channel, 4 waves/block
    pool_kernel<<<NCHAN / 4, 256, 0, stream>>>(x, pooled);
    // 2) excitation: one block per batch
    fc_kernel<<<B_, 256, 0, stream>>>(pooled, w1, b1, w2, b2, s);
    // 3) rescale: one float4 per thread
    scale_kernel<<<(NVEC4 + 255) / 256, 256, 0, stream>>>(x, s, out);
}

// Round 4
// 325.526 us; speedup vs baseline: 1.0242x; 1.0242x over previous
//
#include <hip/hip_runtime.h>
#include <cstdint>

// Problem constants (x: [64, 768, 28, 28] fp32)
#define B_   64
#define C_   768
#define HID_ 192
#define HW_  784                 // 28*28
#define NCHAN (B_ * C_)          // 49152
#define VEC4_PER_CHAN (HW_ / 4)  // 196 float4 per channel
#define NVEC4 (NCHAN * VEC4_PER_CHAN)  // 9,633,792 = 37632 * 256 exactly

typedef float vfloat4 __attribute__((ext_vector_type(4)));  // native vector: ok for nontemporal builtins

// ---------- Kernel 1: global average pool. One wave (64 lanes) per (b,c). ----------
__global__ __launch_bounds__(256) void pool_kernel(const float* __restrict__ x,
                                                   float* __restrict__ pooled) {
    int wave = (blockIdx.x * blockDim.x + threadIdx.x) >> 6;   // channel index b*C+c
    int lane = threadIdx.x & 63;
    const vfloat4* p = (const vfloat4*)(x + (size_t)wave * HW_); // 196 x 16B, 16B-aligned
    float sum = 0.f;
    for (int f = lane; f < VEC4_PER_CHAN; f += 64) {
        vfloat4 v = p[f];
        sum += v.x + v.y + v.z + v.w;
    }
    #pragma unroll
    for (int off = 32; off > 0; off >>= 1) sum += __shfl_down(sum, off, 64);
    if (lane == 0) pooled[wave] = sum * (1.0f / (float)HW_);
}

// ---------- Kernel 2: FC1+ReLU -> FC2+hardsigmoid. One 768-thread block per batch. ----
// Phase1: hidden-unit dot (len 768) split across 4 threads (4x shorter dep chain,
// 12 waves/block vs 4 before -> latency hiding on the 64-block grid).
__global__ __launch_bounds__(768) void fc_kernel(const float* __restrict__ pooled,
                                                 const float* __restrict__ w1,
                                                 const float* __restrict__ b1,
                                                 const float* __restrict__ w2,
                                                 const float* __restrict__ b2,
                                                 float* __restrict__ s_out) {
    __shared__ float sp[C_];         // pooled row
    __shared__ float part[768];      // 4 partials per hidden unit
    __shared__ float sh[HID_];       // hidden activations
    int b = blockIdx.x;
    int t = threadIdx.x;

    sp[t] = pooled[b * C_ + t];
    __syncthreads();

    // Phase 1: hidden h = t>>2, quarter q = t&3 covers floats [q*192, q*192+192)
    {
        int h = t >> 2, q = t & 3;
        const vfloat4* row = (const vfloat4*)(w1 + (size_t)h * C_) + q * 48;
        const float*   pp  = &sp[q * 192];
        float acc = 0.f;
        #pragma unroll 4
        for (int f = 0; f < 48; ++f) {
            vfloat4 v = row[f];
            acc += v.x * pp[f*4+0] + v.y * pp[f*4+1] + v.z * pp[f*4+2] + v.w * pp[f*4+3];
        }
        part[t] = acc;
    }
    __syncthreads();
    if (t < HID_) {
        float hsum = part[4*t] + part[4*t+1] + part[4*t+2] + part[4*t+3] + b1[t];
        sh[t] = hsum > 0.f ? hsum : 0.f;
    }
    __syncthreads();

    // Phase 2: one output channel per thread (768 threads, 48 float4 each)
    {
        const vfloat4* row = (const vfloat4*)(w2 + (size_t)t * HID_);
        float acc = 0.f;
        #pragma unroll 4
        for (int f = 0; f < 48; ++f) {
            vfloat4 v = row[f];
            acc += v.x * sh[f*4+0] + v.y * sh[f*4+1] + v.z * sh[f*4+2] + v.w * sh[f*4+3];
        }
        float z = acc + b2[t];
        float sg = z * (1.0f / 6.0f) + 0.5f;
        sg = sg < 0.f ? 0.f : (sg > 1.f ? 1.f : sg);
        s_out[b * C_ + t] = sg;
    }
}

// ---------- Kernel 3: out = x * s[b,c], one float4 per thread ----------
// Non-temporal store for `out` (write-once, never read) keeps x L3-resident.
__global__ __launch_bounds__(256) void scale_kernel(const float* __restrict__ x,
                                                    const float* __restrict__ s,
                                                    float* __restrict__ out) {
    int f = blockIdx.x * 256 + threadIdx.x;       // grid sized exactly: no bounds check
    float sc = s[f / VEC4_PER_CHAN];              // constant divide -> magic mul
    vfloat4 v = ((const vfloat4*)x)[f];
    v *= sc;
    __builtin_nontemporal_store(v, (vfloat4*)out + f);
}

extern "C" void kernel_launch(void* const* d_in, const int* in_sizes, int n_in,
                              void* d_out, int out_size, void* d_ws, size_t ws_size,
                              hipStream_t stream) {
    const float* x  = (const float*)d_in[0];
    const float* w1 = (const float*)d_in[1];
    const float* b1 = (const float*)d_in[2];
    const float* w2 = (const float*)d_in[3];
    const float* b2 = (const float*)d_in[4];
    float* out = (float*)d_out;

    float* pooled = (float*)d_ws;             // 49152 fp32 = 192 KiB
    float* s      = (float*)d_ws + NCHAN;     // 49152 fp32 = 192 KiB

    pool_kernel<<<NCHAN / 4, 256, 0, stream>>>(x, pooled);
    fc_kernel<<<B_, 768, 0, stream>>>(pooled, w1, b1, w2, b2, s);
    scale_kernel<<<NVEC4 / 256, 256, 0, stream>>>(x, s, out);
}